// Round 1
// baseline (457.791 us; speedup 1.0000x reference)
//
#include <hip/hip_runtime.h>

// R-GCN layer: out[v] = sum_{e: dst[e]=v} norm[e] * (h[src[e]] @ W[rel[e]])
// Strategy:
//   1) zero out + counters
//   2) histogram edges by rel (32 buckets)
//   3) exclusive scan (32 entries, trivial)
//   4) scatter edges into rel-sorted order (block-aggregated atomics)
//   5) per-rel MFMA GEMM: gather h rows (bf16), W[r] B-fragments in registers,
//      C = A*B via mfma_f32_16x16x32_bf16, epilogue scales by norm and
//      atomicAdd-scatters rows to out[dst].

#define N_NODES 50000
#define N_EDGES 1600000
#define D 64
#define N_REL 32

#define HIST_BLOCKS 782          // ceil(1.6M / 2048)
#define CHUNK 512                // edges per GEMM block
#define MAXTILES 105             // ceil(53760/512): covers count up to 53760 per rel

typedef __attribute__((ext_vector_type(8))) __bf16 bf16x8;
typedef __attribute__((ext_vector_type(4))) float f32x4;

// ws layout (bytes):
//   [0,128)      g_count[32]
//   [128,256)    g_base[32]
//   [256,384)    g_cursor[32]
//   [4096, ...)  bsrc[N_EDGES] ints, then bdst[N_EDGES] ints, then bnorm[N_EDGES] floats

__global__ __launch_bounds__(256) void k_zero(float* __restrict__ out, int* __restrict__ counters) {
    int i = blockIdx.x * blockDim.x + threadIdx.x;
    ((float4*)out)[i] = make_float4(0.f, 0.f, 0.f, 0.f);   // grid sized exactly: 800000 float4
    if (blockIdx.x == 0 && threadIdx.x < 96) counters[threadIdx.x] = 0;
}

__global__ __launch_bounds__(256) void k_hist(const int* __restrict__ rel, int* __restrict__ g_count) {
    __shared__ int lc[N_REL];
    if (threadIdx.x < N_REL) lc[threadIdx.x] = 0;
    __syncthreads();
    int ebase = blockIdx.x * 2048;
    #pragma unroll
    for (int rnd = 0; rnd < 8; ++rnd) {
        int e = ebase + rnd * 256 + threadIdx.x;
        if (e < N_EDGES) atomicAdd(&lc[rel[e]], 1);
    }
    __syncthreads();
    if (threadIdx.x < N_REL) atomicAdd(&g_count[threadIdx.x], lc[threadIdx.x]);
}

__global__ void k_scan(const int* __restrict__ g_count, int* __restrict__ g_base,
                       int* __restrict__ g_cursor) {
    if (threadIdx.x == 0) {
        int acc = 0;
        for (int r = 0; r < N_REL; ++r) {
            g_base[r] = acc;
            g_cursor[r] = acc;
            acc += g_count[r];
        }
    }
}

__global__ __launch_bounds__(256) void k_scatter(
        const int* __restrict__ src, const int* __restrict__ dst,
        const int* __restrict__ rel, const float* __restrict__ norm,
        int* __restrict__ g_cursor,
        int* __restrict__ bsrc, int* __restrict__ bdst, float* __restrict__ bnorm) {
    __shared__ int lc[N_REL];
    __shared__ int lbase[N_REL];
    if (threadIdx.x < N_REL) lc[threadIdx.x] = 0;
    __syncthreads();
    int ebase = blockIdx.x * 2048;
    int myr[8], mypos[8];
    #pragma unroll
    for (int rnd = 0; rnd < 8; ++rnd) {
        int e = ebase + rnd * 256 + threadIdx.x;
        myr[rnd] = -1;
        if (e < N_EDGES) {
            myr[rnd] = rel[e];
            mypos[rnd] = atomicAdd(&lc[myr[rnd]], 1);
        }
    }
    __syncthreads();
    if (threadIdx.x < N_REL) lbase[threadIdx.x] = atomicAdd(&g_cursor[threadIdx.x], lc[threadIdx.x]);
    __syncthreads();
    #pragma unroll
    for (int rnd = 0; rnd < 8; ++rnd) {
        if (myr[rnd] >= 0) {
            int e = ebase + rnd * 256 + threadIdx.x;
            int p = lbase[myr[rnd]] + mypos[rnd];
            bsrc[p] = src[e];
            bdst[p] = dst[e];
            bnorm[p] = norm[e];
        }
    }
}

__global__ __launch_bounds__(256) void k_gemm(
        const float* __restrict__ h, const float* __restrict__ W,
        const int* __restrict__ g_base, const int* __restrict__ g_count,
        const int* __restrict__ bsrc, const int* __restrict__ bdst,
        const float* __restrict__ bnorm, float* __restrict__ out) {
    const int r = blockIdx.y;
    const int cnt = g_count[r];
    const int chunk0 = blockIdx.x * CHUNK;
    if (chunk0 >= cnt || cnt <= 0) return;
    const int base_r = g_base[r];
    const int lane = threadIdx.x & 63;
    const int w = threadIdx.x >> 6;
    const int m = lane & 15;      // A row / C col index
    const int q = lane >> 4;      // quad

    // B fragments for W[r]: B[k][n] = W[r][k][n].
    // Lane holds, for frag (kt,nt): element j at k = kt*32 + q*8 + j, n = nt*16 + m.
    const float* Wr = W + (size_t)r * D * D;
    bf16x8 Bfrag[2][4];
    #pragma unroll
    for (int kt = 0; kt < 2; ++kt) {
        #pragma unroll
        for (int nt = 0; nt < 4; ++nt) {
            bf16x8 b;
            #pragma unroll
            for (int j = 0; j < 8; ++j) {
                b[j] = (__bf16)Wr[(kt * 32 + q * 8 + j) * D + nt * 16 + m];
            }
            Bfrag[kt][nt] = b;
        }
    }

    const int end = min(cnt, chunk0 + CHUNK);
    const f32x4 vzero = {0.f, 0.f, 0.f, 0.f};

    for (int e0 = chunk0; e0 < end; e0 += 64) {
        // A gather: lane's row is edge (e0 + w*16 + m), k = kt*32 + q*8 + j
        int er = e0 + w * 16 + m;
        int idx = base_r + min(er, cnt - 1);
        int s = bsrc[idx];
        const float* hrow = h + (size_t)s * D;

        f32x4 acc[4];
        #pragma unroll
        for (int nt = 0; nt < 4; ++nt) acc[nt] = vzero;

        #pragma unroll
        for (int kt = 0; kt < 2; ++kt) {
            const float4* ap = (const float4*)(hrow + kt * 32 + q * 8);
            float4 a0 = ap[0];
            float4 a1 = ap[1];
            bf16x8 a;
            a[0] = (__bf16)a0.x; a[1] = (__bf16)a0.y; a[2] = (__bf16)a0.z; a[3] = (__bf16)a0.w;
            a[4] = (__bf16)a1.x; a[5] = (__bf16)a1.y; a[6] = (__bf16)a1.z; a[7] = (__bf16)a1.w;
            #pragma unroll
            for (int nt = 0; nt < 4; ++nt)
                acc[nt] = __builtin_amdgcn_mfma_f32_16x16x32_bf16(a, Bfrag[kt][nt], acc[nt], 0, 0, 0);
        }

        // Epilogue: C row = q*4 + reg (edge within wave tile), col = nt*16 + m
        #pragma unroll
        for (int reg = 0; reg < 4; ++reg) {
            int mc = q * 4 + reg;
            int erc = e0 + w * 16 + mc;
            if (erc < cnt) {
                int eidx = base_r + erc;
                float nv = bnorm[eidx];
                int dv = bdst[eidx];
                float* orow = out + (size_t)dv * D + m;
                #pragma unroll
                for (int nt = 0; nt < 4; ++nt)
                    atomicAdd(orow + nt * 16, acc[nt][reg] * nv);
            }
        }
    }
}

extern "C" void kernel_launch(void* const* d_in, const int* in_sizes, int n_in,
                              void* d_out, int out_size, void* d_ws, size_t ws_size,
                              hipStream_t stream) {
    const float* h    = (const float*)d_in[0];
    const float* W    = (const float*)d_in[1];
    const int*   src  = (const int*)d_in[2];
    const int*   dst  = (const int*)d_in[3];
    const int*   rel  = (const int*)d_in[4];
    const float* norm = (const float*)d_in[5];
    float* out = (float*)d_out;

    char* ws = (char*)d_ws;
    int* g_count  = (int*)(ws);
    int* g_base   = (int*)(ws + 128);
    int* g_cursor = (int*)(ws + 256);
    int* bsrc     = (int*)(ws + 4096);
    int* bdst     = bsrc + N_EDGES;
    float* bnorm  = (float*)(bdst + N_EDGES);

    // 1) zero out (3.2M floats = 800000 float4) + counters
    k_zero<<<3125, 256, 0, stream>>>(out, g_count);
    // 2) histogram by rel
    k_hist<<<HIST_BLOCKS, 256, 0, stream>>>(rel, g_count);
    // 3) scan
    k_scan<<<1, 64, 0, stream>>>(g_count, g_base, g_cursor);
    // 4) scatter into rel buckets
    k_scatter<<<HIST_BLOCKS, 256, 0, stream>>>(src, dst, rel, norm, g_cursor, bsrc, bdst, bnorm);
    // 5) per-rel MFMA gemm + atomic scatter
    dim3 grid(MAXTILES, N_REL);
    k_gemm<<<grid, 256, 0, stream>>>(h, W, g_base, g_count, bsrc, bdst, bnorm, out);
}